// Round 5
// baseline (161.075 us; speedup 1.0000x reference)
//
#include <hip/hip_runtime.h>
#include <hip/hip_bf16.h>

// BatchTripletLoss on MI355X — round 5: 32x32x16 MFMA + race-fixed staging.
// 256^2 triangular blocks (bn>=bm), BK=64, 8 waves (2M x 4N), 2 dbuf x 4 half-slots.
// 4 phases/KT: {ds-reads, [stage], barrier, setprio, 8x mfma_32x32x16, setprio, barrier}.
// Staging: B halves in P2, A halves in P3 (strictly after last-read barrier -> WAR-safe).
// Counted vmcnt(8) once per KT. Both-sides XOR swizzle. XCD-chunked grid.

#define NROWS 8192
#define DIM   1024
#define BT    256
#define BK    64
#define NKT   (DIM / BK)            // 16 K-tiles
#define NBT   (NROWS / BT)          // 32 tile-rows
#define NTRI  (NBT * (NBT + 1) / 2) // 528 blocks

constexpr float EPS = 1e-6f;
constexpr float MARGIN = 0.5f;

typedef __attribute__((ext_vector_type(8))) short short8;
typedef __attribute__((ext_vector_type(16))) float f32x16;

__device__ __forceinline__ unsigned short f2bf_rne(float f) {
    unsigned u = __float_as_uint(f);
    u += 0x7fffu + ((u >> 16) & 1u);
    return (unsigned short)(u >> 16);
}

// ---------------- kernel 1: per-row stats + bf16 conversion ----------------
__global__ void prep_kernel(const float* __restrict__ X, const float* __restrict__ P,
                            unsigned short* __restrict__ Xb,
                            float* __restrict__ cj, float* __restrict__ basei,
                            float* __restrict__ posd, int* __restrict__ valid)
{
    const int tid  = threadIdx.x;
    const int w    = tid >> 6;
    const int lane = tid & 63;
    const int row  = blockIdx.x * 4 + w;
    const float* xr = X + (size_t)row * DIM;

    float sq = 0.f, sm = 0.f, pd = 0.f;
    bool eq = true;
    #pragma unroll
    for (int it = 0; it < 4; ++it) {
        const int idx = it * 256 + lane * 4;
        const float4 x = *(const float4*)(xr + idx);
        const float4 p = *(const float4*)(P + idx);
        sq += x.x*x.x + x.y*x.y + x.z*x.z + x.w*x.w;
        sm += x.x + x.y + x.z + x.w;
        const float d0 = x.x - p.x + EPS, d1 = x.y - p.y + EPS;
        const float d2 = x.z - p.z + EPS, d3 = x.w - p.w + EPS;
        pd += d0*d0 + d1*d1 + d2*d2 + d3*d3;
        eq = eq && (x.x == p.x) && (x.y == p.y) && (x.z == p.z) && (x.w == p.w);
        ushort4 b;
        b.x = f2bf_rne(x.x); b.y = f2bf_rne(x.y); b.z = f2bf_rne(x.z); b.w = f2bf_rne(x.w);
        *(ushort4*)(Xb + (size_t)row * DIM + idx) = b;
    }
    #pragma unroll
    for (int off = 32; off >= 1; off >>= 1) {
        sq += __shfl_xor(sq, off);
        sm += __shfl_xor(sm, off);
        pd += __shfl_xor(pd, off);
    }
    const bool alleq = __all(eq);
    if (lane == 0) {
        cj[row]    = sq - 2.f * EPS * sm;
        basei[row] = sq + 2.f * EPS * sm + (float)DIM * EPS * EPS;
        posd[row]  = sqrtf(pd);
        valid[row] = alleq ? 0 : 1;
    }
}

// ---------------- kernel 2: 32x32x16-MFMA deep-pipelined symmetric GEMM + row/col max ----------------
// LDS half-slot = 128 rows x 64 K bf16 = 1024 chunks of 16B. Swizzle: logical (r,c)
// chunk at phys p = r*8 + (c ^ (r&7)). gload_lds writes phys-linear, source pre-permuted.
__global__ __launch_bounds__(512, 2) void gemm_max_kernel(
        const unsigned short* __restrict__ Xb,
        const float* __restrict__ cj,
        float* __restrict__ partmax)
{
    // [buf][slot: A0,A1,B0,B1][1024 chunks * 8 ushort]
    __shared__ alignas(16) unsigned short lds[2][4][8192];
    __shared__ float partrow[4][BT];
    __shared__ float partcol[2][BT];

    const int tid  = threadIdx.x;
    const int lane = tid & 63;
    const int wid  = tid >> 6;        // 0..7
    const int wm   = wid >> 2;        // 0..1  (M half: 128 rows)
    const int wn   = wid & 3;         // 0..3  (N quarter: 64 cols)
    const int cl   = lane & 31;       // 32x32 frag row/col index
    const int hi   = lane >> 5;       // k-half selector

    // XCD-chunked bijective triangular decode (528 = 8 * 66)
    const int t0 = (blockIdx.x & 7) * (NTRI / 8) + (blockIdx.x >> 3);
    int bm = (int)(32.5f - sqrtf(1056.25f - 2.f * (float)t0));
    if (bm < 0) bm = 0;
    if (bm > NBT - 1) bm = NBT - 1;
    while (bm > 0 && (65 * bm - bm * bm) / 2 > t0) --bm;
    while ((65 * (bm + 1) - (bm + 1) * (bm + 1)) / 2 <= t0) ++bm;
    const int bn = bm + (t0 - (65 * bm - bm * bm) / 2);
    const bool diag = (bm == bn);
    const int Mbase = bm * BT, Nbase = bn * BT;

    f32x16 acc[4][2];   // [mtile 32-rows][ntile 32-cols]
    #pragma unroll
    for (int m = 0; m < 4; ++m)
        #pragma unroll
        for (int n = 0; n < 2; ++n)
            #pragma unroll
            for (int r = 0; r < 16; ++r)
                acc[m][n][r] = 0.f;

    #define STAGE(BUF, SLOT, GBASE, KT) do {                                                  \
        _Pragma("unroll")                                                                     \
        for (int inst_ = 0; inst_ < 2; ++inst_) {                                             \
            const int q_ = inst_ * 512 + tid;                                                 \
            const int r_ = q_ >> 3;                                                           \
            const int c_ = (q_ & 7) ^ (r_ & 7);                                               \
            const unsigned short* src_ = Xb + (size_t)((GBASE) + r_) * DIM + (KT) * BK + c_ * 8; \
            unsigned short* dst_ = &lds[BUF][SLOT][(inst_ * 512 + wid * 64) * 8];             \
            __builtin_amdgcn_global_load_lds((const __attribute__((address_space(1))) void*)src_, \
                                             (__attribute__((address_space(3))) void*)dst_, 16, 0, 0); \
        }                                                                                     \
    } while (0)

    // frag read helpers: r = row within 128-row half-slot, kc = 8-elem K-chunk (0..7)
    #define LDA(PTR, R, KC) (*(const short8*)((PTR) + (((R) * 8 + ((KC) ^ ((R) & 7)))) * 8))

    // prologue: stage kt0 then kt1 (8+8 loads); vmcnt(8) -> kt0 landed
    STAGE(0, 0, Mbase, 0); STAGE(0, 1, Mbase + 128, 0);
    STAGE(0, 2, Nbase, 0); STAGE(0, 3, Nbase + 128, 0);
    STAGE(1, 0, Mbase, 1); STAGE(1, 1, Mbase + 128, 1);
    STAGE(1, 2, Nbase, 1); STAGE(1, 3, Nbase + 128, 1);
    asm volatile("s_waitcnt vmcnt(8)" ::: "memory");
    __builtin_amdgcn_s_barrier();
    __builtin_amdgcn_sched_barrier(0);

    const int cl0 = (wn & 1) * 64;          // wave's col base within its B half-slot

    for (int kt = 0; kt < NKT; ++kt) {
        const int b = kt & 1;
        const unsigned short* Ah = &lds[b][wm][0];
        const unsigned short* Bh = &lds[b][2 + (wn >> 1)][0];
        const bool st = (kt + 2 < NKT);     // block-uniform
        const int kp = kt + 2;
        short8 af[2][4], bf0[4], bf1[4];

        // ---- P0: read A-mh0 (8) + B-nt0 (4); MFMA Q(mh0, nt0)
        #pragma unroll
        for (int mt2 = 0; mt2 < 2; ++mt2)
            #pragma unroll
            for (int ks = 0; ks < 4; ++ks)
                af[mt2][ks] = LDA(Ah, mt2 * 32 + cl, ks * 2 + hi);
        #pragma unroll
        for (int ks = 0; ks < 4; ++ks)
            bf0[ks] = LDA(Bh, cl0 + cl, ks * 2 + hi);
        __builtin_amdgcn_s_barrier();
        __builtin_amdgcn_s_setprio(1);
        #pragma unroll
        for (int ks = 0; ks < 4; ++ks)
            #pragma unroll
            for (int mt2 = 0; mt2 < 2; ++mt2)
                acc[mt2][0] = __builtin_amdgcn_mfma_f32_32x32x16_bf16(af[mt2][ks], bf0[ks], acc[mt2][0], 0, 0, 0);
        __builtin_amdgcn_s_setprio(0);
        __builtin_amdgcn_s_barrier();

        // ---- P1: read B-nt1 (4); MFMA Q(mh0, nt1)
        #pragma unroll
        for (int ks = 0; ks < 4; ++ks)
            bf1[ks] = LDA(Bh, cl0 + 32 + cl, ks * 2 + hi);
        __builtin_amdgcn_s_barrier();
        __builtin_amdgcn_s_setprio(1);
        #pragma unroll
        for (int ks = 0; ks < 4; ++ks)
            #pragma unroll
            for (int mt2 = 0; mt2 < 2; ++mt2)
                acc[mt2][1] = __builtin_amdgcn_mfma_f32_32x32x16_bf16(af[mt2][ks], bf1[ks], acc[mt2][1], 0, 0, 0);
        __builtin_amdgcn_s_setprio(0);
        __builtin_amdgcn_s_barrier();

        // ---- P2: read A-mh1 (8); stage B0,B1(kt+2) [B last read in P1 -> safe]; MFMA Q(mh1, nt1)
        #pragma unroll
        for (int mt2 = 0; mt2 < 2; ++mt2)
            #pragma unroll
            for (int ks = 0; ks < 4; ++ks)
                af[mt2][ks] = LDA(Ah, 64 + mt2 * 32 + cl, ks * 2 + hi);
        if (st) { STAGE(b, 2, Nbase, kp); STAGE(b, 3, Nbase + 128, kp); }
        __builtin_amdgcn_s_barrier();
        __builtin_amdgcn_s_setprio(1);
        #pragma unroll
        for (int ks = 0; ks < 4; ++ks)
            #pragma unroll
            for (int mt2 = 0; mt2 < 2; ++mt2)
                acc[2 + mt2][1] = __builtin_amdgcn_mfma_f32_32x32x16_bf16(af[mt2][ks], bf1[ks], acc[2 + mt2][1], 0, 0, 0);
        __builtin_amdgcn_s_setprio(0);
        __builtin_amdgcn_s_barrier();

        // ---- P3: stage A0,A1(kt+2) [A last read in P2 -> safe]; MFMA Q(mh1, nt0) — regs only
        if (st) { STAGE(b, 0, Mbase, kp); STAGE(b, 1, Mbase + 128, kp); }
        __builtin_amdgcn_s_setprio(1);
        #pragma unroll
        for (int ks = 0; ks < 4; ++ks)
            #pragma unroll
            for (int mt2 = 0; mt2 < 2; ++mt2)
                acc[2 + mt2][0] = __builtin_amdgcn_mfma_f32_32x32x16_bf16(af[mt2][ks], bf0[ks], acc[2 + mt2][0], 0, 0, 0);
        __builtin_amdgcn_s_setprio(0);

        // tile switch: ensure kt+1 landed; keep kt+2's 8 loads in flight
        if (kt < NKT - 2)       asm volatile("s_waitcnt vmcnt(8)" ::: "memory");
        else if (kt == NKT - 2) asm volatile("s_waitcnt vmcnt(0)" ::: "memory");
        __builtin_amdgcn_s_barrier();
        __builtin_amdgcn_sched_barrier(0);
    }
    #undef STAGE
    #undef LDA

    // ---- epilogue. 32x32 C/D layout: col = lane&31, row = (reg&3) + 8*(reg>>2) + 4*(lane>>5)
    float cv[2];
    #pragma unroll
    for (int n = 0; n < 2; ++n)
        cv[n] = cj[Nbase + wn * 64 + n * 32 + cl];

    // (a) row-max over this wave's 64 cols, combine across wn via LDS
    #pragma unroll
    for (int mt = 0; mt < 4; ++mt) {
        #pragma unroll
        for (int r = 0; r < 16; ++r) {
            const int lrow = wm * 128 + mt * 32 + (r & 3) + 8 * (r >> 2) + 4 * hi;
            float v = -__builtin_inff();
            #pragma unroll
            for (int n = 0; n < 2; ++n) {
                float val = cv[n] - 2.f * acc[mt][n][r];
                if (diag && lrow == wn * 64 + n * 32 + cl) val = -__builtin_inff();
                v = fmaxf(v, val);
            }
            #pragma unroll
            for (int off = 16; off >= 1; off >>= 1)
                v = fmaxf(v, __shfl_xor(v, off));   // reduce over 32 cols (cl)
            if (cl == 0) partrow[wn][lrow] = v;     // lanes 0 and 32 hold different rows
        }
    }

    // (b) transposed col-max over this wave's 128 rows, combine across wm
    if (!diag) {
        float vt[2] = { -__builtin_inff(), -__builtin_inff() };
        #pragma unroll
        for (int mt = 0; mt < 4; ++mt) {
            #pragma unroll
            for (int r = 0; r < 16; ++r) {
                const float ci = cj[Mbase + wm * 128 + mt * 32 + (r & 3) + 8 * (r >> 2) + 4 * hi];
                #pragma unroll
                for (int n = 0; n < 2; ++n)
                    vt[n] = fmaxf(vt[n], ci - 2.f * acc[mt][n][r]);
            }
        }
        #pragma unroll
        for (int n = 0; n < 2; ++n) {
            vt[n] = fmaxf(vt[n], __shfl_xor(vt[n], 32));   // combine the two hi halves
            if (hi == 0) partcol[wm][wn * 64 + n * 32 + cl] = vt[n];
        }
    }
    __syncthreads();

    if (tid < BT) {
        const float v = fmaxf(fmaxf(partrow[0][tid], partrow[1][tid]),
                              fmaxf(partrow[2][tid], partrow[3][tid]));
        partmax[(size_t)bn * NROWS + Mbase + tid] = v;
    } else if (!diag) {
        const int c = tid - BT;
        partmax[(size_t)bm * NROWS + Nbase + c] = fmaxf(partcol[0][c], partcol[1][c]);
    }
}

// ---------------- kernel 3: per-row finalize + block partial sums ----------------
__global__ void finalize1_kernel(const float* __restrict__ partmax,
                                 const float* __restrict__ basei,
                                 const float* __restrict__ posd,
                                 const int* __restrict__ valid,
                                 float* __restrict__ partials)
{
    const int tid = threadIdx.x;
    const int row = blockIdx.x * 256 + tid;
    float m = -__builtin_inff();
    #pragma unroll 8
    for (int p = 0; p < NBT; ++p)
        m = fmaxf(m, partmax[(size_t)p * NROWS + row]);
    const float d2 = m + basei[row];
    const float mn = sqrtf(fmaxf(d2, 0.f));
    float loss = fmaxf(posd[row] - mn + MARGIN, 0.f);
    float cnt = 1.f;
    if (!valid[row]) { loss = 0.f; cnt = 0.f; }
    #pragma unroll
    for (int off = 32; off >= 1; off >>= 1) {
        loss += __shfl_xor(loss, off);
        cnt  += __shfl_xor(cnt, off);
    }
    __shared__ float sl[4], sc[4];
    const int w = tid >> 6, lane = tid & 63;
    if (lane == 0) { sl[w] = loss; sc[w] = cnt; }
    __syncthreads();
    if (tid == 0) {
        partials[blockIdx.x * 2]     = sl[0] + sl[1] + sl[2] + sl[3];
        partials[blockIdx.x * 2 + 1] = sc[0] + sc[1] + sc[2] + sc[3];
    }
}

// ---------------- kernel 4: final scalar ----------------
__global__ void finalize2_kernel(const float* __restrict__ partials, float* __restrict__ out)
{
    const int tid = threadIdx.x;   // 64 threads
    float l = 0.f, c = 0.f;
    if (tid < 32) { l = partials[tid * 2]; c = partials[tid * 2 + 1]; }
    #pragma unroll
    for (int off = 32; off >= 1; off >>= 1) {
        l += __shfl_xor(l, off);
        c += __shfl_xor(c, off);
    }
    if (tid == 0) out[0] = l / c;
}

extern "C" void kernel_launch(void* const* d_in, const int* in_sizes, int n_in,
                              void* d_out, int out_size, void* d_ws, size_t ws_size,
                              hipStream_t stream)
{
    const float* X = (const float*)d_in[0];   // [8192,1024] f32
    const float* P = (const float*)d_in[1];   // [1024] f32
    float* out = (float*)d_out;
    char* ws = (char*)d_ws;

    unsigned short* Xb = (unsigned short*)ws;                                // 16 MB bf16
    size_t off = (size_t)NROWS * DIM * sizeof(unsigned short);
    float* cj    = (float*)(ws + off);  off += (size_t)NROWS * 4;
    float* basei = (float*)(ws + off);  off += (size_t)NROWS * 4;
    float* posd  = (float*)(ws + off);  off += (size_t)NROWS * 4;
    int*   valid = (int*)(ws + off);    off += (size_t)NROWS * 4;
    float* partmax = (float*)(ws + off); off += (size_t)NBT * NROWS * 4;     // 1 MB
    float* partials = (float*)(ws + off);

    prep_kernel<<<NROWS / 4, 256, 0, stream>>>(X, P, Xb, cj, basei, posd, valid);
    gemm_max_kernel<<<NTRI, 512, 0, stream>>>(Xb, cj, partmax);
    finalize1_kernel<<<NROWS / 256, 256, 0, stream>>>(partmax, basei, posd, valid, partials);
    finalize2_kernel<<<1, 64, 0, stream>>>(partials, out);
}

// Round 6
// 122.268 us; speedup vs baseline: 1.3174x; 1.3174x over previous
//
#include <hip/hip_runtime.h>
#include <hip/hip_bf16.h>

// BatchTripletLoss on MI355X — round 6: R4 base + evened ds_reads + fewer barriers.
// 256^2 triangular blocks (bn>=bm), BK=64, 8 waves (2M x 4N), 16x16x32 MFMA,
// 2 dbuf x 4 half-slots. Phases per KT (4 barriers total):
//   P0: read af_lo(8);              MFMA Q(lo,n0..1); barrier
//   P1: read bf1(4);                MFMA Q(lo,n2..3); barrier
//   P2: read af_hi(8); stage B(kt+2); MFMA Q(hi,n2..3); barrier
//   P3: stage A(kt+2); MFMA Q(hi,n0..1); vmcnt(8); prefetch bf0(kt+1) from other buf; barrier
// bf0 for KT's first quadrant is prefetched at the PREVIOUS KT's P3 (after counted
// vmcnt guarantees that buffer landed). Both-sides XOR swizzle; XCD-chunked grid.

#define NROWS 8192
#define DIM   1024
#define BT    256
#define BK    64
#define NKT   (DIM / BK)            // 16 K-tiles
#define NBT   (NROWS / BT)          // 32 tile-rows
#define NTRI  (NBT * (NBT + 1) / 2) // 528 blocks

constexpr float EPS = 1e-6f;
constexpr float MARGIN = 0.5f;

typedef __attribute__((ext_vector_type(8))) short short8;
typedef __attribute__((ext_vector_type(4))) float f32x4;

__device__ __forceinline__ unsigned short f2bf_rne(float f) {
    unsigned u = __float_as_uint(f);
    u += 0x7fffu + ((u >> 16) & 1u);
    return (unsigned short)(u >> 16);
}

// ---------------- kernel 1: per-row stats + bf16 conversion ----------------
__global__ void prep_kernel(const float* __restrict__ X, const float* __restrict__ P,
                            unsigned short* __restrict__ Xb,
                            float* __restrict__ cj, float* __restrict__ basei,
                            float* __restrict__ posd, int* __restrict__ valid)
{
    const int tid  = threadIdx.x;
    const int w    = tid >> 6;
    const int lane = tid & 63;
    const int row  = blockIdx.x * 4 + w;
    const float* xr = X + (size_t)row * DIM;

    float sq = 0.f, sm = 0.f, pd = 0.f;
    bool eq = true;
    #pragma unroll
    for (int it = 0; it < 4; ++it) {
        const int idx = it * 256 + lane * 4;
        const float4 x = *(const float4*)(xr + idx);
        const float4 p = *(const float4*)(P + idx);
        sq += x.x*x.x + x.y*x.y + x.z*x.z + x.w*x.w;
        sm += x.x + x.y + x.z + x.w;
        const float d0 = x.x - p.x + EPS, d1 = x.y - p.y + EPS;
        const float d2 = x.z - p.z + EPS, d3 = x.w - p.w + EPS;
        pd += d0*d0 + d1*d1 + d2*d2 + d3*d3;
        eq = eq && (x.x == p.x) && (x.y == p.y) && (x.z == p.z) && (x.w == p.w);
        ushort4 b;
        b.x = f2bf_rne(x.x); b.y = f2bf_rne(x.y); b.z = f2bf_rne(x.z); b.w = f2bf_rne(x.w);
        *(ushort4*)(Xb + (size_t)row * DIM + idx) = b;
    }
    #pragma unroll
    for (int off = 32; off >= 1; off >>= 1) {
        sq += __shfl_xor(sq, off);
        sm += __shfl_xor(sm, off);
        pd += __shfl_xor(pd, off);
    }
    const bool alleq = __all(eq);
    if (lane == 0) {
        cj[row]    = sq - 2.f * EPS * sm;
        basei[row] = sq + 2.f * EPS * sm + (float)DIM * EPS * EPS;
        posd[row]  = sqrtf(pd);
        valid[row] = alleq ? 0 : 1;
    }
}

// ---------------- kernel 2: deep-pipelined symmetric GEMM + row/col max ----------------
// LDS half-slot = 128 rows x 64 K bf16 = 1024 chunks of 16B. Swizzle: logical (r,c)
// chunk at phys p = r*8 + (c ^ (r&7)). gload_lds writes phys-linear, source pre-permuted.
__global__ __launch_bounds__(512, 2) void gemm_max_kernel(
        const unsigned short* __restrict__ Xb,
        const float* __restrict__ cj,
        float* __restrict__ partmax)
{
    // [buf][slot: A0,A1,B0,B1][1024 chunks * 8 ushort]
    __shared__ alignas(16) unsigned short lds[2][4][8192];
    __shared__ float partrow[4][BT];
    __shared__ float partcol[2][BT];

    const int tid  = threadIdx.x;
    const int lane = tid & 63;
    const int wid  = tid >> 6;        // 0..7
    const int wm   = wid >> 2;        // 0..1  (M half: 128 rows)
    const int wn   = wid & 3;         // 0..3  (N quarter: 64 cols)
    const int l15  = lane & 15;
    const int lk   = lane >> 4;       // 0..3
    const int cx0  = lk ^ (l15 & 7);          // K-chunk for ks=0
    const int cx1  = (4 + lk) ^ (l15 & 7);    // ks=1

    // XCD-chunked bijective triangular decode (528 = 8 * 66)
    const int t0 = (blockIdx.x & 7) * (NTRI / 8) + (blockIdx.x >> 3);
    int bm = (int)(32.5f - sqrtf(1056.25f - 2.f * (float)t0));
    if (bm < 0) bm = 0;
    if (bm > NBT - 1) bm = NBT - 1;
    while (bm > 0 && (65 * bm - bm * bm) / 2 > t0) --bm;
    while ((65 * (bm + 1) - (bm + 1) * (bm + 1)) / 2 <= t0) ++bm;
    const int bn = bm + (t0 - (65 * bm - bm * bm) / 2);
    const bool diag = (bm == bn);
    const int Mbase = bm * BT, Nbase = bn * BT;

    f32x4 acc[8][4];
    #pragma unroll
    for (int m = 0; m < 8; ++m)
        #pragma unroll
        for (int n = 0; n < 4; ++n)
            acc[m][n] = (f32x4){0.f, 0.f, 0.f, 0.f};

    #define STAGE(BUF, SLOT, GBASE, KT) do {                                                  \
        _Pragma("unroll")                                                                     \
        for (int inst_ = 0; inst_ < 2; ++inst_) {                                             \
            const int q_ = inst_ * 512 + tid;                                                 \
            const int r_ = q_ >> 3;                                                           \
            const int c_ = (q_ & 7) ^ (r_ & 7);                                               \
            const unsigned short* src_ = Xb + (size_t)((GBASE) + r_) * DIM + (KT) * BK + c_ * 8; \
            unsigned short* dst_ = &lds[BUF][SLOT][(inst_ * 512 + wid * 64) * 8];             \
            __builtin_amdgcn_global_load_lds((const __attribute__((address_space(1))) void*)src_, \
                                             (__attribute__((address_space(3))) void*)dst_, 16, 0, 0); \
        }                                                                                     \
    } while (0)

    // prologue: stage kt0 then kt1 (8+8 loads); vmcnt(8) -> kt0 landed
    STAGE(0, 0, Mbase, 0); STAGE(0, 1, Mbase + 128, 0);
    STAGE(0, 2, Nbase, 0); STAGE(0, 3, Nbase + 128, 0);
    STAGE(1, 0, Mbase, 1); STAGE(1, 1, Mbase + 128, 1);
    STAGE(1, 2, Nbase, 1); STAGE(1, 3, Nbase + 128, 1);
    asm volatile("s_waitcnt vmcnt(8)" ::: "memory");
    __builtin_amdgcn_s_barrier();
    __builtin_amdgcn_sched_barrier(0);

    const int cl0 = (wn & 1) * 64;          // wave's col base within its B half-slot

    // initial bf0 (kt=0) from buf0
    short8 bf0[4], bf1[4], af[8];
    {
        const unsigned short* B0 = &lds[0][2 + (wn >> 1)][0];
        #pragma unroll
        for (int nt = 0; nt < 2; ++nt) {
            bf0[nt * 2]     = *(const short8*)(B0 + ((cl0 + nt * 16 + l15) * 8 + cx0) * 8);
            bf0[nt * 2 + 1] = *(const short8*)(B0 + ((cl0 + nt * 16 + l15) * 8 + cx1) * 8);
        }
    }

    for (int kt = 0; kt < NKT; ++kt) {
        const int b = kt & 1;
        const unsigned short* Ah = &lds[b][wm][0];
        const unsigned short* Bh = &lds[b][2 + (wn >> 1)][0];
        const unsigned short* Bn = &lds[b ^ 1][2 + (wn >> 1)][0];   // next KT's B
        const bool st = (kt + 2 < NKT);     // block-uniform
        const int kp = kt + 2;

        // ---- P0: read af_lo (8); MFMA Q(lo, n0..1)  [bf0 prefetched at prev P3]
        #pragma unroll
        for (int mt = 0; mt < 4; ++mt) {
            af[mt * 2]     = *(const short8*)(Ah + ((mt * 16 + l15) * 8 + cx0) * 8);
            af[mt * 2 + 1] = *(const short8*)(Ah + ((mt * 16 + l15) * 8 + cx1) * 8);
        }
        __builtin_amdgcn_s_setprio(1);
        #pragma unroll
        for (int ks = 0; ks < 2; ++ks)
            #pragma unroll
            for (int mt = 0; mt < 4; ++mt)
                #pragma unroll
                for (int nt = 0; nt < 2; ++nt)
                    acc[mt][nt] = __builtin_amdgcn_mfma_f32_16x16x32_bf16(af[mt*2+ks], bf0[nt*2+ks], acc[mt][nt], 0, 0, 0);
        __builtin_amdgcn_s_setprio(0);
        __builtin_amdgcn_s_barrier();

        // ---- P1: read bf1 (4); MFMA Q(lo, n2..3)
        #pragma unroll
        for (int nt = 0; nt < 2; ++nt) {
            bf1[nt * 2]     = *(const short8*)(Bh + ((cl0 + 32 + nt * 16 + l15) * 8 + cx0) * 8);
            bf1[nt * 2 + 1] = *(const short8*)(Bh + ((cl0 + 32 + nt * 16 + l15) * 8 + cx1) * 8);
        }
        __builtin_amdgcn_s_setprio(1);
        #pragma unroll
        for (int ks = 0; ks < 2; ++ks)
            #pragma unroll
            for (int mt = 0; mt < 4; ++mt)
                #pragma unroll
                for (int nt = 0; nt < 2; ++nt)
                    acc[mt][2+nt] = __builtin_amdgcn_mfma_f32_16x16x32_bf16(af[mt*2+ks], bf1[nt*2+ks], acc[mt][2+nt], 0, 0, 0);
        __builtin_amdgcn_s_setprio(0);
        __builtin_amdgcn_s_barrier();

        // ---- P2: read af_hi (8); stage B(kt+2) [B reads done @P1-barrier]; MFMA Q(hi, n2..3)
        #pragma unroll
        for (int mt = 0; mt < 4; ++mt) {
            af[mt * 2]     = *(const short8*)(Ah + ((64 + mt * 16 + l15) * 8 + cx0) * 8);
            af[mt * 2 + 1] = *(const short8*)(Ah + ((64 + mt * 16 + l15) * 8 + cx1) * 8);
        }
        if (st) { STAGE(b, 2, Nbase, kp); STAGE(b, 3, Nbase + 128, kp); }
        __builtin_amdgcn_s_setprio(1);
        #pragma unroll
        for (int ks = 0; ks < 2; ++ks)
            #pragma unroll
            for (int mt = 0; mt < 4; ++mt)
                #pragma unroll
                for (int nt = 0; nt < 2; ++nt)
                    acc[4+mt][2+nt] = __builtin_amdgcn_mfma_f32_16x16x32_bf16(af[mt*2+ks], bf1[nt*2+ks], acc[4+mt][2+nt], 0, 0, 0);
        __builtin_amdgcn_s_setprio(0);
        __builtin_amdgcn_s_barrier();

        // ---- P3: stage A(kt+2) [A reads done @P2-barrier]; MFMA Q(hi, n0..1);
        //          counted vmcnt; prefetch bf0(kt+1) from other buffer
        if (st) { STAGE(b, 0, Mbase, kp); STAGE(b, 1, Mbase + 128, kp); }
        __builtin_amdgcn_s_setprio(1);
        #pragma unroll
        for (int ks = 0; ks < 2; ++ks)
            #pragma unroll
            for (int mt = 0; mt < 4; ++mt)
                #pragma unroll
                for (int nt = 0; nt < 2; ++nt)
                    acc[4+mt][nt] = __builtin_amdgcn_mfma_f32_16x16x32_bf16(af[mt*2+ks], bf0[nt*2+ks], acc[4+mt][nt], 0, 0, 0);
        __builtin_amdgcn_s_setprio(0);

        if (kt <= NKT - 3)      asm volatile("s_waitcnt vmcnt(8)" ::: "memory");
        else                    asm volatile("s_waitcnt vmcnt(0)" ::: "memory");
        if (kt < NKT - 1) {
            #pragma unroll
            for (int nt = 0; nt < 2; ++nt) {
                bf0[nt * 2]     = *(const short8*)(Bn + ((cl0 + nt * 16 + l15) * 8 + cx0) * 8);
                bf0[nt * 2 + 1] = *(const short8*)(Bn + ((cl0 + nt * 16 + l15) * 8 + cx1) * 8);
            }
        }
        __builtin_amdgcn_s_barrier();
        __builtin_amdgcn_sched_barrier(0);
    }
    #undef STAGE

    // ---- epilogue. C/D layout: col = l15, row = lk*4 + reg. acc[m][n]: row m*16, col n*16
    float cv[4];
    #pragma unroll
    for (int n = 0; n < 4; ++n)
        cv[n] = cj[Nbase + wn * 64 + n * 16 + l15];

    // (a) row-max over this wave's 64 cols, combine across wn via LDS
    #pragma unroll
    for (int m = 0; m < 8; ++m) {
        #pragma unroll
        for (int r = 0; r < 4; ++r) {
            const int lrow = wm * 128 + m * 16 + lk * 4 + r;
            float v = -__builtin_inff();
            #pragma unroll
            for (int n = 0; n < 4; ++n) {
                float val = cv[n] - 2.f * acc[m][n][r];
                if (diag && lrow == wn * 64 + n * 16 + l15) val = -__builtin_inff();
                v = fmaxf(v, val);
            }
            #pragma unroll
            for (int off = 8; off >= 1; off >>= 1)
                v = fmaxf(v, __shfl_xor(v, off));
            if (l15 == 0) partrow[wn][lrow] = v;
        }
    }

    // (b) transposed col-max over this wave's 128 rows, combine across wm
    if (!diag) {
        float vt[4];
        #pragma unroll
        for (int n = 0; n < 4; ++n) vt[n] = -__builtin_inff();
        #pragma unroll
        for (int m = 0; m < 8; ++m) {
            #pragma unroll
            for (int r = 0; r < 4; ++r) {
                const float ci = cj[Mbase + wm * 128 + m * 16 + lk * 4 + r];
                #pragma unroll
                for (int n = 0; n < 4; ++n)
                    vt[n] = fmaxf(vt[n], ci - 2.f * acc[m][n][r]);
            }
        }
        #pragma unroll
        for (int n = 0; n < 4; ++n) {
            vt[n] = fmaxf(vt[n], __shfl_xor(vt[n], 16));
            vt[n] = fmaxf(vt[n], __shfl_xor(vt[n], 32));
            if (lk == 0) partcol[wm][wn * 64 + n * 16 + l15] = vt[n];
        }
    }
    __syncthreads();

    if (tid < BT) {
        const float v = fmaxf(fmaxf(partrow[0][tid], partrow[1][tid]),
                              fmaxf(partrow[2][tid], partrow[3][tid]));
        partmax[(size_t)bn * NROWS + Mbase + tid] = v;
    } else if (!diag) {
        const int c = tid - BT;
        partmax[(size_t)bm * NROWS + Nbase + c] = fmaxf(partcol[0][c], partcol[1][c]);
    }
}

// ---------------- kernel 3: per-row finalize + block partial sums ----------------
__global__ void finalize1_kernel(const float* __restrict__ partmax,
                                 const float* __restrict__ basei,
                                 const float* __restrict__ posd,
                                 const int* __restrict__ valid,
                                 float* __restrict__ partials)
{
    const int tid = threadIdx.x;
    const int row = blockIdx.x * 256 + tid;
    float m = -__builtin_inff();
    #pragma unroll 8
    for (int p = 0; p < NBT; ++p)
        m = fmaxf(m, partmax[(size_t)p * NROWS + row]);
    const float d2 = m + basei[row];
    const float mn = sqrtf(fmaxf(d2, 0.f));
    float loss = fmaxf(posd[row] - mn + MARGIN, 0.f);
    float cnt = 1.f;
    if (!valid[row]) { loss = 0.f; cnt = 0.f; }
    #pragma unroll
    for (int off = 32; off >= 1; off >>= 1) {
        loss += __shfl_xor(loss, off);
        cnt  += __shfl_xor(cnt, off);
    }
    __shared__ float sl[4], sc[4];
    const int w = tid >> 6, lane = tid & 63;
    if (lane == 0) { sl[w] = loss; sc[w] = cnt; }
    __syncthreads();
    if (tid == 0) {
        partials[blockIdx.x * 2]     = sl[0] + sl[1] + sl[2] + sl[3];
        partials[blockIdx.x * 2 + 1] = sc[0] + sc[1] + sc[2] + sc[3];
    }
}

// ---------------- kernel 4: final scalar ----------------
__global__ void finalize2_kernel(const float* __restrict__ partials, float* __restrict__ out)
{
    const int tid = threadIdx.x;   // 64 threads
    float l = 0.f, c = 0.f;
    if (tid < 32) { l = partials[tid * 2]; c = partials[tid * 2 + 1]; }
    #pragma unroll
    for (int off = 32; off >= 1; off >>= 1) {
        l += __shfl_xor(l, off);
        c += __shfl_xor(c, off);
    }
    if (tid == 0) out[0] = l / c;
}

extern "C" void kernel_launch(void* const* d_in, const int* in_sizes, int n_in,
                              void* d_out, int out_size, void* d_ws, size_t ws_size,
                              hipStream_t stream)
{
    const float* X = (const float*)d_in[0];   // [8192,1024] f32
    const float* P = (const float*)d_in[1];   // [1024] f32
    float* out = (float*)d_out;
    char* ws = (char*)d_ws;

    unsigned short* Xb = (unsigned short*)ws;                                // 16 MB bf16
    size_t off = (size_t)NROWS * DIM * sizeof(unsigned short);
    float* cj    = (float*)(ws + off);  off += (size_t)NROWS * 4;
    float* basei = (float*)(ws + off);  off += (size_t)NROWS * 4;
    float* posd  = (float*)(ws + off);  off += (size_t)NROWS * 4;
    int*   valid = (int*)(ws + off);    off += (size_t)NROWS * 4;
    float* partmax = (float*)(ws + off); off += (size_t)NBT * NROWS * 4;     // 1 MB
    float* partials = (float*)(ws + off);

    prep_kernel<<<NROWS / 4, 256, 0, stream>>>(X, P, Xb, cj, basei, posd, valid);
    gemm_max_kernel<<<NTRI, 512, 0, stream>>>(Xb, cj, partmax);
    finalize1_kernel<<<NROWS / 256, 256, 0, stream>>>(partmax, basei, posd, valid, partials);
    finalize2_kernel<<<1, 64, 0, stream>>>(partials, out);
}